// Round 3
// baseline (822.129 us; speedup 1.0000x reference)
//
#include <hip/hip_runtime.h>

// Inception Temporal Layer — 3 causal VALID conv1d + leaky_relu(0.01).
// x[8192][512][4] f32; w1[16][4][6]; w2[16][16][4]; w3[16][16][13]; out[8192][3][48][16].
// Dependency cone: o3[t<48] <- o2[0..142] (even only) <- o1[0..151] <- x[0..458].
//
// Design (round 3): kill the LDS-issue bound.
//  - weights + x read from GLOBAL into registers (L1/L2 cached; per-co rows are
//    contiguous & 16B-aligned in the natural layouts)
//  - o1/o2even in LDS as [t][20] (stride 20: 16B-aligned float4 chunks, all
//    wave access patterns land <=2 lanes/bank)
//  - all LDS reads are ds_read_b128 (4 ci per read), 16 FMAs per read
//  - output tile staged in LDS, copied out as contiguous float4 (1KB/wave-instr)
//  - 128 threads = 2 waves per row; co=tid&15, tg=tid>>4 (0..7)

#define LREL(v) ((v) > 0.0f ? (v) : 0.01f * (v))

__global__ __launch_bounds__(128, 3) void itl_kernel(
    const float* __restrict__ x,
    const float* __restrict__ w1, const float* __restrict__ b1,
    const float* __restrict__ w2, const float* __restrict__ b2,
    const float* __restrict__ w3, const float* __restrict__ b3,
    float* __restrict__ out)
{
    __shared__ float o1s[152 * 20];   // o1[t][ci], stride 20
    __shared__ float o2e[72 * 20];    // o2[2*t2][ci], even rows only, stride 20
    __shared__ float outs[2304];      // [3][48][16] staged output tile

    const int tid = threadIdx.x;
    const int n   = blockIdx.x;
    const int co  = tid & 15;
    const int tg  = tid >> 4;         // 0..7

    const float4* x4 = reinterpret_cast<const float4*>(x) + (size_t)n * 512;

    // ================= stage 1: o1[t] = leaky(sum_{c<4,k<6} x[3t+k][c]*w1[co][c][k]+b1)
    // thread owns t = 19*tg + r, r<19 (covers 0..151)
    {
        float w1r[24];  // w1r[c*6+k]
        const float4* w14 = reinterpret_cast<const float4*>(w1) + co * 6;
        #pragma unroll
        for (int q = 0; q < 6; ++q) {
            float4 v = w14[q];
            w1r[4*q+0] = v.x; w1r[4*q+1] = v.y; w1r[4*q+2] = v.z; w1r[4*q+3] = v.w;
        }
        float acc1[19];
        const float bias = b1[co];
        #pragma unroll
        for (int r = 0; r < 19; ++r) acc1[r] = bias;

        // stream positions p = 57*tg + i, i<60 (p <= 458 < 512); each feeds k=i%3 (r=i/3)
        // and k=i%3+3 (r=i/3-1), 4 channels each
        #pragma unroll
        for (int i = 0; i < 60; ++i) {
            float4 xv = x4[57 * tg + i];
            const int r1 = i / 3, k1 = i % 3;
            if (r1 < 19) {
                acc1[r1] = fmaf(xv.x, w1r[ 0 + k1], acc1[r1]);
                acc1[r1] = fmaf(xv.y, w1r[ 6 + k1], acc1[r1]);
                acc1[r1] = fmaf(xv.z, w1r[12 + k1], acc1[r1]);
                acc1[r1] = fmaf(xv.w, w1r[18 + k1], acc1[r1]);
            }
            const int r2 = r1 - 1, k2 = k1 + 3;
            if (r2 >= 0) {
                acc1[r2] = fmaf(xv.x, w1r[ 0 + k2], acc1[r2]);
                acc1[r2] = fmaf(xv.y, w1r[ 6 + k2], acc1[r2]);
                acc1[r2] = fmaf(xv.z, w1r[12 + k2], acc1[r2]);
                acc1[r2] = fmaf(xv.w, w1r[18 + k2], acc1[r2]);
            }
        }
        #pragma unroll
        for (int r = 0; r < 19; ++r) {
            const int t = 19 * tg + r;
            const float v = LREL(acc1[r]);
            o1s[t * 20 + co] = v;
            if (t < 48) outs[t * 16 + co] = v;   // scale 0
        }
    }
    __syncthreads();

    // ================= stage 2: o2[j] = leaky(sum_{ci<16,k<4} o1[j+2k][ci]*w2[co][ci][k]+b2)
    // thread owns j = 18*tg + r, r<18 (covers 0..143); reads p = 18*tg+i, i<24 (p<=149)
    {
        float w2r[64];  // w2r[ci*4+k]
        const float4* w24 = reinterpret_cast<const float4*>(w2) + co * 16;
        #pragma unroll
        for (int q = 0; q < 16; ++q) {
            float4 v = w24[q];
            w2r[4*q+0] = v.x; w2r[4*q+1] = v.y; w2r[4*q+2] = v.z; w2r[4*q+3] = v.w;
        }
        float acc2[18];
        const float bias = b2[co];
        #pragma unroll
        for (int r = 0; r < 18; ++r) acc2[r] = bias;

        #pragma unroll
        for (int i = 0; i < 24; ++i) {
            const float* row = &o1s[(18 * tg + i) * 20];
            float4 v0 = *(const float4*)(row);
            float4 v1 = *(const float4*)(row + 4);
            float4 v2 = *(const float4*)(row + 8);
            float4 v3 = *(const float4*)(row + 12);
            const float vrow[16] = {v0.x, v0.y, v0.z, v0.w, v1.x, v1.y, v1.z, v1.w,
                                    v2.x, v2.y, v2.z, v2.w, v3.x, v3.y, v3.z, v3.w};
            #pragma unroll
            for (int k = 0; k < 4; ++k) {
                const int r = i - 2 * k;
                if (r >= 0 && r < 18) {
                    #pragma unroll
                    for (int ci = 0; ci < 16; ++ci)
                        acc2[r] = fmaf(vrow[ci], w2r[ci * 4 + k], acc2[r]);
                }
            }
        }
        #pragma unroll
        for (int r = 0; r < 18; ++r) {
            const int j = 18 * tg + r;
            const float v = LREL(acc2[r]);
            if ((j & 1) == 0) o2e[(j >> 1) * 20 + co] = v;
            if (j < 48) outs[768 + j * 16 + co] = v;   // scale 1
        }
    }
    __syncthreads();

    // ================= stage 3: o3[t] = leaky(sum_{ci<16,k<13} o2[2t+4k][ci]*w3[co][ci][k]+b3)
    // thread owns t = 6*tg + r, r<6; even rows t2 = 6*tg + m, m<30 (t2 <= 71)
    {
        float acc3[6];
        const float bias = b3[co];
        #pragma unroll
        for (int r = 0; r < 6; ++r) acc3[r] = bias;

        const float4* w34 = reinterpret_cast<const float4*>(w3) + co * 52;
        #pragma unroll 1
        for (int c3 = 0; c3 < 4; ++c3) {   // ci chunk: ci = 4*c3 + cl
            float wr[52];  // wr[cl*13 + k]
            #pragma unroll
            for (int q = 0; q < 13; ++q) {
                float4 v = w34[c3 * 13 + q];
                wr[4*q+0] = v.x; wr[4*q+1] = v.y; wr[4*q+2] = v.z; wr[4*q+3] = v.w;
            }
            #pragma unroll
            for (int m = 0; m < 30; ++m) {
                float4 v = *(const float4*)(&o2e[(6 * tg + m) * 20 + 4 * c3]);
                const float vr[4] = {v.x, v.y, v.z, v.w};
                #pragma unroll
                for (int k = 0; k < 13; ++k) {
                    const int r = m - 2 * k;
                    if (r >= 0 && r < 6) {
                        #pragma unroll
                        for (int cl = 0; cl < 4; ++cl)
                            acc3[r] = fmaf(vr[cl], wr[cl * 13 + k], acc3[r]);
                    }
                }
            }
        }
        #pragma unroll
        for (int r = 0; r < 6; ++r) {
            const int t = 6 * tg + r;
            outs[1536 + t * 16 + co] = LREL(acc3[r]);   // scale 2
        }
    }
    __syncthreads();

    // ================= coalesced copy-out: 576 float4 = 9216B, 1KB per wave-instr
    float4* outn4 = reinterpret_cast<float4*>(out + (size_t)n * 2304);
    const float4* outs4 = reinterpret_cast<const float4*>(outs);
    #pragma unroll
    for (int q = tid; q < 576; q += 128) outn4[q] = outs4[q];
}

extern "C" void kernel_launch(void* const* d_in, const int* in_sizes, int n_in,
                              void* d_out, int out_size, void* d_ws, size_t ws_size,
                              hipStream_t stream) {
    const float* x  = (const float*)d_in[0];
    const float* w1 = (const float*)d_in[1];
    const float* b1 = (const float*)d_in[2];
    const float* w2 = (const float*)d_in[3];
    const float* b2 = (const float*)d_in[4];
    const float* w3 = (const float*)d_in[5];
    const float* b3 = (const float*)d_in[6];
    float* out = (float*)d_out;

    const int N = 16 * 64 * 8;  // 8192 rows
    itl_kernel<<<N, 128, 0, stream>>>(x, w1, b1, w2, b2, w3, b3, out);
}

// Round 4
// 164.563 us; speedup vs baseline: 4.9958x; 4.9958x over previous
//
#include <hip/hip_runtime.h>

// Inception Temporal Layer — 3 causal VALID conv1d + leaky_relu(0.01).
// x[8192][512][4] f32; w1[16][4][6]; w2[16][16][4]; w3[16][16][13]; out[8192][3][48][16].
// Cone: o3[t<48] <- even o2[0..142] <- o1[0..148] <- x[0..458].
//
// Round 4 design: lane = time position, acc[16] = all output channels.
//  - per (ci,k) step: 1 ds_read_b32 (lane-stride-1) + 16 FMA with wave-uniform
//    weight (SGPR via s_load from pre-transposed d_ws) -> FMA:ds = 16:1
//  - one WAVE per row, private LDS slice, zero __syncthreads
//  - x read global->regs (6 float4/lane); outputs transposed via LDS tmp,
//    stored as contiguous float4 (no write amplification)
//  - all register arrays <= 16+24 floats, statically indexed (no scratch)

#define LREL(v) fmaxf((v), 0.01f * (v))

// ws float layout:
//   [0..383]     w1t[(ch*6+k)*16+co]
//   [384..1407]  w2t[(ci*4+k)*16+co]
//   [1408..4735] w3t[(ci*13+k)*16+co]
//   [4736..4751] b1   [4752..4767] b2   [4768..4783] b3
__global__ void wtrans_kernel(const float* __restrict__ w1, const float* __restrict__ b1,
                              const float* __restrict__ w2, const float* __restrict__ b2,
                              const float* __restrict__ w3, const float* __restrict__ b3,
                              float* __restrict__ ws) {
    const int tid = threadIdx.x;
    for (int t = tid; t < 384; t += 256)  { int co = t / 24,  r = t % 24;  ws[r * 16 + co] = w1[t]; }
    for (int t = tid; t < 1024; t += 256) { int co = t >> 6,  r = t & 63;  ws[384 + r * 16 + co] = w2[t]; }
    for (int t = tid; t < 3328; t += 256) { int co = t / 208, r = t % 208; ws[1408 + r * 16 + co] = w3[t]; }
    if (tid < 16) { ws[4736 + tid] = b1[tid]; ws[4752 + tid] = b2[tid]; ws[4768 + tid] = b3[tid]; }
}

// copy one 48x16 scale tile (held in tmp[48][20]) to global as contiguous float4
__device__ __forceinline__ void copy_scale(const float* __restrict__ tmp,
                                           float* __restrict__ dst, int lane) {
    float4* d4 = reinterpret_cast<float4*>(dst);
    #pragma unroll
    for (int q = 0; q < 3; ++q) {
        const int f4 = q * 64 + lane;                 // 0..191 -> 768 floats
        const int t  = f4 >> 2;
        const int cb = (f4 & 3) << 2;                 // co base 0,4,8,12 (16B aligned)
        d4[f4] = *reinterpret_cast<const float4*>(&tmp[t * 20 + cb]);
    }
}

__global__ __launch_bounds__(128, 2) void itl_kernel(
    const float* __restrict__ x,
    const float* __restrict__ wt,
    float* __restrict__ out)
{
    __shared__ float lds[2 * 4560];                   // 36,480 B/block
    const int lane = threadIdx.x & 63;
    const int wv   = threadIdx.x >> 6;
    const int n    = blockIdx.x * 2 + wv;             // one row per WAVE

    float* o1  = &lds[wv * 4560];                     // [16][152]  (o1[ci*152+t])
    float* o2e = o1 + 2432;                           // [16][73]   (even j at slot j/2)
    float* tmp = o2e + 1168;                          // [48][20]   transpose buffer

    const float4* x4 = reinterpret_cast<const float4*>(x) + (size_t)n * 512;
    const float* w1t = wt;
    const float* w2t = wt + 384;
    const float* w3t = wt + 1408;
    float* outn = out + (size_t)n * 2304;

    // ---------------- stage 1: o1[t][co], t<152 (3 chunks of 64 lanes) ----------
    #pragma unroll
    for (int c = 0; c < 3; ++c) {
        const int t = 64 * c + lane;
        if (t < 152) {
            float xv[24];                             // x[3t..3t+5][0..3], static idx
            #pragma unroll
            for (int k = 0; k < 6; ++k)
                *reinterpret_cast<float4*>(&xv[4 * k]) = x4[3 * t + k];
            float acc[16];
            #pragma unroll
            for (int co = 0; co < 16; ++co) acc[co] = wt[4736 + co];
            #pragma unroll
            for (int ch = 0; ch < 4; ++ch)
                #pragma unroll
                for (int k = 0; k < 6; ++k) {
                    const float xval = xv[4 * k + ch];
                    #pragma unroll
                    for (int co = 0; co < 16; ++co)
                        acc[co] = fmaf(xval, w1t[(ch * 6 + k) * 16 + co], acc[co]);
                }
            const bool s0 = (t < 48);
            #pragma unroll
            for (int co = 0; co < 16; ++co) {
                const float v = LREL(acc[co]);
                o1[co * 152 + t] = v;
                if (s0) tmp[t * 20 + co] = v;
            }
        }
    }
    copy_scale(tmp, outn, lane);                      // scale 0

    // ---------------- stage 2 chunk A: j = lane (0..63) -------------------------
    {
        const int j = lane;
        float acc[16];
        #pragma unroll
        for (int co = 0; co < 16; ++co) acc[co] = wt[4752 + co];
        #pragma unroll 2
        for (int ci = 0; ci < 16; ++ci)
            #pragma unroll
            for (int k = 0; k < 4; ++k) {
                const float xval = o1[ci * 152 + j + 2 * k];      // <= 69
                #pragma unroll
                for (int co = 0; co < 16; ++co)
                    acc[co] = fmaf(xval, w2t[(ci * 4 + k) * 16 + co], acc[co]);
            }
        const bool ev = ((j & 1) == 0);
        const bool s1 = (j < 48);
        #pragma unroll
        for (int co = 0; co < 16; ++co) {
            const float v = LREL(acc[co]);
            if (ev) o2e[co * 73 + (j >> 1)] = v;      // slots 0..31
            if (s1) tmp[j * 20 + co] = v;
        }
    }
    copy_scale(tmp, outn + 768, lane);                // scale 1

    // ---------------- stage 2 chunk B: j = 64 + 2*lane (even), lane<40 ----------
    if (lane < 40) {
        const int j = 64 + 2 * lane;                  // 64..142
        float acc[16];
        #pragma unroll
        for (int co = 0; co < 16; ++co) acc[co] = wt[4752 + co];
        #pragma unroll 2
        for (int ci = 0; ci < 16; ++ci)
            #pragma unroll
            for (int k = 0; k < 4; ++k) {
                const float xval = o1[ci * 152 + j + 2 * k];      // <= 148
                #pragma unroll
                for (int co = 0; co < 16; ++co)
                    acc[co] = fmaf(xval, w2t[(ci * 4 + k) * 16 + co], acc[co]);
            }
        #pragma unroll
        for (int co = 0; co < 16; ++co)
            o2e[co * 73 + (j >> 1)] = LREL(acc[co]);  // slots 32..71
    }

    // ---------------- stage 3: t = lane < 48 ------------------------------------
    if (lane < 48) {
        const int t = lane;
        float acc[16];
        #pragma unroll
        for (int co = 0; co < 16; ++co) acc[co] = wt[4768 + co];
        #pragma unroll 2
        for (int ci = 0; ci < 16; ++ci)
            #pragma unroll
            for (int k = 0; k < 13; ++k) {
                const float xval = o2e[ci * 73 + t + 2 * k];      // slot <= 71
                #pragma unroll
                for (int co = 0; co < 16; ++co)
                    acc[co] = fmaf(xval, w3t[(ci * 13 + k) * 16 + co], acc[co]);
            }
        #pragma unroll
        for (int co = 0; co < 16; ++co)
            tmp[t * 20 + co] = LREL(acc[co]);
    }
    copy_scale(tmp, outn + 1536, lane);               // scale 2
}

extern "C" void kernel_launch(void* const* d_in, const int* in_sizes, int n_in,
                              void* d_out, int out_size, void* d_ws, size_t ws_size,
                              hipStream_t stream) {
    const float* x  = (const float*)d_in[0];
    const float* w1 = (const float*)d_in[1];
    const float* b1 = (const float*)d_in[2];
    const float* w2 = (const float*)d_in[3];
    const float* b2 = (const float*)d_in[4];
    const float* w3 = (const float*)d_in[5];
    const float* b3 = (const float*)d_in[6];
    float* out = (float*)d_out;
    float* ws  = (float*)d_ws;                        // needs 4784 floats = 19,136 B

    wtrans_kernel<<<1, 256, 0, stream>>>(w1, b1, w2, b2, w3, b3, ws);
    itl_kernel<<<4096, 128, 0, stream>>>(x, ws, out); // 8192 rows, 1 row/wave
}

// Round 5
// 107.431 us; speedup vs baseline: 7.6526x; 1.5318x over previous
//
#include <hip/hip_runtime.h>

// Inception Temporal Layer — 3 causal VALID conv1d + leaky_relu(0.01).
// x[8192][512][4] f32; w1[16][4][6]; w2[16][16][4]; w3[16][16][13]; out[8192][3][48][16].
// Cone: o3[t<48] <- even o2[0..142] <- o1[0..148] <- x[0..458].
//
// Round 5: one WAVE per row (64-thr blocks), lane = time position, packed-fp32
// accumulators (v_pk_fma_f32) covering all 16 output channels as 8 x float2.
//  - weights pre-transposed into d_ws so co-pairs are contiguous (uniform
//    addresses -> SGPR loads, FMA B-operand wave-uniform)
//  - o1/o2even in LDS [ci][t] (lane-stride-1 reads, conflict-free)
//  - outputs stored directly from acc regs: 4x dwordx4 per lane, 64B/lane
//  - no tmp buffer, no __syncthreads (single wave, in-order LDS pipe)
//  - LDS 14,336 B/block -> 11 blocks/CU = 11 waves/CU

typedef float v2f __attribute__((ext_vector_type(2)));

__device__ __forceinline__ v2f fma2(v2f a, v2f b, v2f c) {
    return __builtin_elementwise_fma(a, b, c);
}
__device__ __forceinline__ v2f lrel2(v2f v) {
    v2f r; r.x = fmaxf(v.x, 0.01f * v.x); r.y = fmaxf(v.y, 0.01f * v.y); return r;
}

// ws float layout:
//   [0..383]     w1t[(ch*6+k)*16+co]
//   [384..1407]  w2t[(ci*4+k)*16+co]
//   [1408..4735] w3t[(ci*13+k)*16+co]
//   [4736..4751] b1   [4752..4767] b2   [4768..4783] b3
__global__ void wtrans_kernel(const float* __restrict__ w1, const float* __restrict__ b1,
                              const float* __restrict__ w2, const float* __restrict__ b2,
                              const float* __restrict__ w3, const float* __restrict__ b3,
                              float* __restrict__ ws) {
    const int tid = threadIdx.x;
    for (int t = tid; t < 384; t += 256)  { int co = t / 24,  r = t % 24;  ws[r * 16 + co] = w1[t]; }
    for (int t = tid; t < 1024; t += 256) { int co = t >> 6,  r = t & 63;  ws[384 + r * 16 + co] = w2[t]; }
    for (int t = tid; t < 3328; t += 256) { int co = t / 208, r = t % 208; ws[1408 + r * 16 + co] = w3[t]; }
    if (tid < 16) { ws[4736 + tid] = b1[tid]; ws[4752 + tid] = b2[tid]; ws[4768 + tid] = b3[tid]; }
}

__device__ __forceinline__ void act_store(const v2f acc[8], float av[16]) {
    #pragma unroll
    for (int p = 0; p < 8; ++p) {
        v2f v = lrel2(acc[p]);
        av[2 * p] = v.x; av[2 * p + 1] = v.y;
    }
}

__global__ __launch_bounds__(64, 3) void itl_kernel(
    const float* __restrict__ x,
    const float* __restrict__ wt,
    float* __restrict__ out)
{
    __shared__ float o1[16 * 152];   // o1[ci*152 + t], t valid 0..151
    __shared__ float o2e[16 * 72];   // even o2 rows: slot j/2, ci*72 + slot

    const int lane = threadIdx.x;    // 0..63, one wave per block
    const int n    = blockIdx.x;     // one row per wave

    const float4* x4  = reinterpret_cast<const float4*>(x) + (size_t)n * 512;
    const v2f* w1t = reinterpret_cast<const v2f*>(wt);            // [(ch*6+k)*8 + p]
    const v2f* w2t = reinterpret_cast<const v2f*>(wt + 384);      // [(ci*4+k)*8 + p]
    const v2f* w3t = reinterpret_cast<const v2f*>(wt + 1408);     // [(ci*13+k)*8 + p]
    const v2f* bs  = reinterpret_cast<const v2f*>(wt + 4736);     // b1:0..7 b2:8..15 b3:16..23
    float* outn = out + (size_t)n * 2304;

    // ---------------- stage 1: o1[t][co], t = 64c + lane < 152 ------------------
    #pragma unroll
    for (int c = 0; c < 3; ++c) {
        const int t = 64 * c + lane;
        if (t < 152) {
            float xv[24];                             // x[3t..3t+5][0..3]
            #pragma unroll
            for (int k = 0; k < 6; ++k)
                *reinterpret_cast<float4*>(&xv[4 * k]) = x4[3 * t + k];
            v2f acc[8];
            #pragma unroll
            for (int p = 0; p < 8; ++p) acc[p] = bs[p];
            #pragma unroll
            for (int ch = 0; ch < 4; ++ch)
                #pragma unroll
                for (int k = 0; k < 6; ++k) {
                    const float xs = xv[4 * k + ch];
                    const v2f xs2 = {xs, xs};
                    #pragma unroll
                    for (int p = 0; p < 8; ++p)
                        acc[p] = fma2(xs2, w1t[(ch * 6 + k) * 8 + p], acc[p]);
                }
            float av[16];
            act_store(acc, av);
            #pragma unroll
            for (int co = 0; co < 16; ++co) o1[co * 152 + t] = av[co];
            if (t < 48) {
                float4* d = reinterpret_cast<float4*>(outn + t * 16);  // scale 0
                #pragma unroll
                for (int q = 0; q < 4; ++q)
                    d[q] = *reinterpret_cast<const float4*>(&av[4 * q]);
            }
        }
    }

    // ---------------- stage 2 chunk A: j = lane (0..63) -------------------------
    {
        const int j = lane;
        v2f acc[8];
        #pragma unroll
        for (int p = 0; p < 8; ++p) acc[p] = bs[8 + p];
        #pragma unroll 2
        for (int ci = 0; ci < 16; ++ci)
            #pragma unroll
            for (int k = 0; k < 4; ++k) {
                const float xs = o1[ci * 152 + j + 2 * k];        // <= 69
                const v2f xs2 = {xs, xs};
                #pragma unroll
                for (int p = 0; p < 8; ++p)
                    acc[p] = fma2(xs2, w2t[(ci * 4 + k) * 8 + p], acc[p]);
            }
        float av[16];
        act_store(acc, av);
        if ((j & 1) == 0) {
            #pragma unroll
            for (int co = 0; co < 16; ++co) o2e[co * 72 + (j >> 1)] = av[co];  // slots 0..31
        }
        if (j < 48) {
            float4* d = reinterpret_cast<float4*>(outn + 768 + j * 16);  // scale 1
            #pragma unroll
            for (int q = 0; q < 4; ++q)
                d[q] = *reinterpret_cast<const float4*>(&av[4 * q]);
        }
    }

    // ---------------- stage 2 chunk B: j = 64 + 2*lane (even), lane<40 ----------
    if (lane < 40) {
        const int j = 64 + 2 * lane;                  // 64..142 even
        v2f acc[8];
        #pragma unroll
        for (int p = 0; p < 8; ++p) acc[p] = bs[8 + p];
        #pragma unroll 2
        for (int ci = 0; ci < 16; ++ci)
            #pragma unroll
            for (int k = 0; k < 4; ++k) {
                const float xs = o1[ci * 152 + j + 2 * k];        // <= 148
                const v2f xs2 = {xs, xs};
                #pragma unroll
                for (int p = 0; p < 8; ++p)
                    acc[p] = fma2(xs2, w2t[(ci * 4 + k) * 8 + p], acc[p]);
            }
        float av[16];
        act_store(acc, av);
        #pragma unroll
        for (int co = 0; co < 16; ++co) o2e[co * 72 + (j >> 1)] = av[co];      // slots 32..71
    }

    // ---------------- stage 3: t = lane < 48 ------------------------------------
    if (lane < 48) {
        const int t = lane;
        v2f acc[8];
        #pragma unroll
        for (int p = 0; p < 8; ++p) acc[p] = bs[16 + p];
        #pragma unroll 2
        for (int ci = 0; ci < 16; ++ci)
            #pragma unroll
            for (int k = 0; k < 13; ++k) {
                const float xs = o2e[ci * 72 + t + 2 * k];        // slot <= 71
                const v2f xs2 = {xs, xs};
                #pragma unroll
                for (int p = 0; p < 8; ++p)
                    acc[p] = fma2(xs2, w3t[(ci * 13 + k) * 8 + p], acc[p]);
            }
        float av[16];
        act_store(acc, av);
        float4* d = reinterpret_cast<float4*>(outn + 1536 + t * 16);  // scale 2
        #pragma unroll
        for (int q = 0; q < 4; ++q)
            d[q] = *reinterpret_cast<const float4*>(&av[4 * q]);
    }
}

extern "C" void kernel_launch(void* const* d_in, const int* in_sizes, int n_in,
                              void* d_out, int out_size, void* d_ws, size_t ws_size,
                              hipStream_t stream) {
    const float* x  = (const float*)d_in[0];
    const float* w1 = (const float*)d_in[1];
    const float* b1 = (const float*)d_in[2];
    const float* w2 = (const float*)d_in[3];
    const float* b2 = (const float*)d_in[4];
    const float* w3 = (const float*)d_in[5];
    const float* b3 = (const float*)d_in[6];
    float* out = (float*)d_out;
    float* ws  = (float*)d_ws;                        // needs 4784 floats = 19,136 B

    wtrans_kernel<<<1, 256, 0, stream>>>(w1, b1, w2, b2, w3, b3, ws);
    itl_kernel<<<8192, 64, 0, stream>>>(x, ws, out);  // 1 row per wave
}